// Round 5
// baseline (243.301 us; speedup 1.0000x reference)
//
#include <hip/hip_runtime.h>
#include <math.h>

#define DIM   256
#define NLVL  5
#define NB1   2048           // pass1 blocks (8192 waves)
#define NW1   (NB1*4)

struct Ptrs {
  const float* p[NLVL];
  const float* W[NLVL];
  const float* b[NLVL];
};

// ---- pass 1: all 5 levels per row, software-pipelined prefetch (MLP=5..10),
//      fused online-softmax partials.
__global__ __launch_bounds__(256) void k_pass1(Ptrs pt, float* __restrict__ logits,
                                               float2* __restrict__ part, int N)
{
  const int lane = threadIdx.x & 63;
  const int wid  = threadIdx.x >> 6;

  float4 wf[NLVL];
  float  bias[NLVL], m[NLVL], s[NLVL];
  #pragma unroll
  for (int l = 0; l < NLVL; l++) {
    wf[l]   = *reinterpret_cast<const float4*>(pt.W[l] + lane * 4);
    bias[l] = *pt.b[l];
    m[l]    = -INFINITY;
    s[l]    = 0.f;
  }

  const int gw = blockIdx.x * 4 + wid;       // 0..8191
  const int off = lane * 4;

  // prologue: prefetch iteration 0 (all waves have gw < N)
  float4 pv[NLVL];
  #pragma unroll
  for (int l = 0; l < NLVL; l++)
    pv[l] = *reinterpret_cast<const float4*>(pt.p[l] + (size_t)gw * DIM + off);
  __builtin_amdgcn_sched_barrier(0);

  for (int i = gw; i < N; i += NW1) {
    // prefetch i+NW1 (clamped; redundant row-0 load on last iter is harmless)
    const int nn = i + NW1;
    const size_t n_next = (nn < N) ? (size_t)nn : 0;
    float4 nx[NLVL];
    #pragma unroll
    for (int l = 0; l < NLVL; l++)
      nx[l] = *reinterpret_cast<const float4*>(pt.p[l] + n_next * DIM + off);
    __builtin_amdgcn_sched_barrier(0);

    // compute on pv (row i)
    float d[NLVL];
    #pragma unroll
    for (int l = 0; l < NLVL; l++)
      d[l] = pv[l].x * wf[l].x + pv[l].y * wf[l].y + pv[l].z * wf[l].z + pv[l].w * wf[l].w;
    #pragma unroll
    for (int o = 32; o; o >>= 1) {           // 5 independent chains (ILP-5)
      #pragma unroll
      for (int l = 0; l < NLVL; l++) d[l] += __shfl_xor(d[l], o);
    }
    #pragma unroll
    for (int l = 0; l < NLVL; l++) d[l] += bias[l];

    // one 5-lane store instead of 5 masked stores
    float sv = d[0];
    sv = (lane == 1) ? d[1] : sv;
    sv = (lane == 2) ? d[2] : sv;
    sv = (lane == 3) ? d[3] : sv;
    sv = (lane == 4) ? d[4] : sv;
    if (lane < NLVL) logits[(size_t)lane * N + i] = sv;

    #pragma unroll
    for (int l = 0; l < NLVL; l++) {         // online softmax update (lane-redundant)
      float Mn = fmaxf(m[l], d[l]);
      s[l] = s[l] * __expf(m[l] - Mn) + __expf(d[l] - Mn);
      m[l] = Mn;
    }

    #pragma unroll
    for (int l = 0; l < NLVL; l++) pv[l] = nx[l];
    __builtin_amdgcn_sched_barrier(0);
  }

  __shared__ float smM[4][NLVL], smS[4][NLVL];
  if (lane == 0) {
    #pragma unroll
    for (int l = 0; l < NLVL; l++) { smM[wid][l] = m[l]; smS[wid][l] = s[l]; }
  }
  __syncthreads();
  if (threadIdx.x < NLVL) {                  // thread l combines 4 waves for level l
    const int l = threadIdx.x;
    float M = smM[0][l], S = smS[0][l];
    #pragma unroll
    for (int i = 1; i < 4; i++) {
      float Mn = fmaxf(M, smM[i][l]);
      if (Mn > -INFINITY) { S = S * __expf(M - Mn) + smS[i][l] * __expf(smM[i][l] - Mn); M = Mn; }
    }
    part[l * NB1 + blockIdx.x] = make_float2(M, S);
  }
}

// ---- combine NB1 partials per level -> (M, S) ----
__global__ __launch_bounds__(320) void k_reduce(const float2* __restrict__ part,
                                                float2* __restrict__ stats)
{
  const int lvl  = threadIdx.x >> 6;
  const int lane = threadIdx.x & 63;
  float m = -INFINITY, s = 0.f;
  for (int i = lane; i < NB1; i += 64) {
    float2 ps = part[lvl * NB1 + i];
    float Mn = fmaxf(m, ps.x);
    if (Mn > -INFINITY) { s = s * __expf(m - Mn) + ps.y * __expf(ps.x - Mn); m = Mn; }
  }
  #pragma unroll
  for (int o = 32; o; o >>= 1) {
    float mo = __shfl_xor(m, o), so = __shfl_xor(s, o);
    float Mn = fmaxf(m, mo);
    if (Mn > -INFINITY) { s = s * __expf(m - Mn) + so * __expf(mo - Mn); m = Mn; }
  }
  if (lane == 0) stats[lvl] = make_float2(m, s);
}

// ---- pass 2: weights + fused output ----
__global__ __launch_bounds__(256) void k_pass2(Ptrs pt, const float* __restrict__ logits,
                                               const float2* __restrict__ stats,
                                               float* __restrict__ out, int N)
{
  const int lane = threadIdx.x & 63;
  const int wid  = threadIdx.x >> 6;
  float M[NLVL], Si[NLVL];
  #pragma unroll
  for (int l = 0; l < NLVL; l++) { float2 st = stats[l]; M[l] = st.x; Si[l] = 1.f / st.y; }

  const int gw = blockIdx.x * 4 + wid;
  const int nw = gridDim.x * 4;
  for (int n = gw; n < N; n += nw) {
    float wl[NLVL], t = 0.f;
    #pragma unroll
    for (int l = 0; l < NLVL; l++) {
      float e = __expf(logits[(size_t)l * N + n] - M[l]) * Si[l];
      wl[l] = e; t += e;
    }
    const float inv = 1.f / t;
    float4 acc = make_float4(0.f, 0.f, 0.f, 0.f);
    #pragma unroll
    for (int l = 0; l < NLVL; l++) {
      float4 pv = *reinterpret_cast<const float4*>(pt.p[l] + (size_t)n * DIM + lane * 4);
      float c = wl[l] * inv;
      acc.x += c * pv.x; acc.y += c * pv.y; acc.z += c * pv.z; acc.w += c * pv.w;
    }
    *reinterpret_cast<float4*>(out + (size_t)n * DIM + lane * 4) = acc;
  }
}

extern "C" void kernel_launch(void* const* d_in, const int* in_sizes, int n_in,
                              void* d_out, int out_size, void* d_ws, size_t ws_size,
                              hipStream_t stream)
{
  Ptrs pt;
  for (int l = 0; l < NLVL; l++) {
    pt.p[l] = (const float*)d_in[l];
    pt.W[l] = (const float*)d_in[5 + 2 * l];
    pt.b[l] = (const float*)d_in[6 + 2 * l];
  }
  const int N = in_sizes[0] / DIM;             // 100000

  char* ws = (char*)d_ws;
  size_t logits_bytes = ((size_t)NLVL * N * sizeof(float) + 255) & ~(size_t)255;
  float*  logits = (float*)ws;
  float2* part   = (float2*)(ws + logits_bytes);
  float2* stats  = part + NLVL * NB1;

  k_pass1 <<<NB1,  256, 0, stream>>>(pt, logits, part, N);
  k_reduce<<<1,    320, 0, stream>>>(part, stats);
  k_pass2 <<<2048, 256, 0, stream>>>(pt, logits, stats, (float*)d_out, N);
}

// Round 6
// 222.995 us; speedup vs baseline: 1.0911x; 1.0911x over previous
//
#include <hip/hip_runtime.h>
#include <math.h>

#define DIM   256
#define NLVL  5
#define CH    8              // rows per staged chunk
#define RST   260            // padded LDS row stride (floats): 1040 B, 16B-aligned
#define NB1   1024           // pass1 blocks (128 thr = 2 waves each; 33.3 KB LDS -> 4/CU exact fit)
#define NSB   64             // stats blocks per level

struct Ptrs {
  const float* p[NLVL];
  const float* W[NLVL];
  const float* b[NLVL];
};

// DMA one CH-row chunk (level-contiguous rows) into wave-private LDS buffer.
// Each global_load_lds(16B) stages one full 1 KB row: lane i contributes
// bytes [i*16, i*16+16) -> LDS base + i*16 (linear, wave-uniform base).
#define ISSUE_CHUNK(bufp, c)                                                        \
  do {                                                                              \
    const float* gb_ = p + (size_t)(c) * (CH * DIM) + (lane << 2);                  \
    _Pragma("unroll")                                                               \
    for (int rr_ = 0; rr_ < CH; ++rr_)                                              \
      __builtin_amdgcn_global_load_lds(                                             \
          (const __attribute__((address_space(1))) void*)(const void*)(gb_ + rr_ * DIM), \
          (__attribute__((address_space(3))) void*)(void*)((bufp) + rr_ * RST),     \
          16, 0, 0);                                                                \
  } while (0)

// ---- pass 1: logits via LDS-DMA double buffer. No barriers, wave-private LDS. ----
__global__ __launch_bounds__(128) void k_pass1(Ptrs pt, float* __restrict__ logits, int N)
{
  __shared__ float tile[2][2][CH * RST];       // [wave][buf][rows] = 33,280 B/block

  const int lane = threadIdx.x & 63;
  const int wid  = threadIdx.x >> 6;           // 0..1
  const int bid  = blockIdx.x;
  const int lvl  = bid % NLVL;
  const int lb   = bid / NLVL;
  const float* __restrict__ p = pt.p[lvl];
  const float* __restrict__ W = pt.W[lvl];
  const float bias = *pt.b[lvl];

  const int e = lane & 7;                      // column-eighth
  const int r = lane >> 3;                     // row within chunk 0..7

  float4 wreg[8];                              // W float4s at indices e+8k (interleaved)
  #pragma unroll
  for (int k = 0; k < 8; k++)
    wreg[k] = *reinterpret_cast<const float4*>(W + 4 * (e + 8 * k));

  const int blocks_l = (NB1 - lvl + NLVL - 1) / NLVL;   // 205 or 204
  const int S   = blocks_l * 2;                // wave stride in chunks
  const int w0  = lb * 2 + wid;                // this wave's first chunk
  const int NCH = N / CH;                      // 12500 (N divisible by 8)

  float* tb0 = &tile[wid][0][0];
  float* tb1 = &tile[wid][1][0];

  // prologue: fill both buffers' pipelines (every wave has >= 30 chunks)
  ISSUE_CHUNK(tb0, w0);
  if (w0 + S < NCH) ISSUE_CHUNK(tb1, w0 + S);

  int buf = 0;
  for (int c = w0; c < NCH; c += S) {
    // wait for current buffer's 8 DMAs: the (up to) 8 newest outstanding loads
    // belong to the other buffer, so vmcnt(8) guarantees ours retired.
    if (c + S < NCH) { asm volatile("s_waitcnt vmcnt(8)" ::: "memory"); }
    else             { asm volatile("s_waitcnt vmcnt(0)" ::: "memory"); }
    __builtin_amdgcn_sched_barrier(0);

    const float* tb = buf ? tb1 : tb0;
    float acc = 0.f;
    #pragma unroll
    for (int k = 0; k < 8; k++) {              // 8 ds_read_b128, 2-way banks (free)
      float4 a = *reinterpret_cast<const float4*>(tb + r * RST + 4 * (e + 8 * k));
      acc += a.x * wreg[k].x + a.y * wreg[k].y + a.z * wreg[k].z + a.w * wreg[k].w;
    }
    acc += __shfl_xor(acc, 1);                 // reduce over e within 8-lane group
    acc += __shfl_xor(acc, 2);
    acc += __shfl_xor(acc, 4);
    if (e == 0)                                // 8 lanes -> 8 consecutive floats
      logits[(size_t)lvl * N + c * CH + r] = acc + bias;

    __builtin_amdgcn_sched_barrier(0);
    if (c + 2 * S < NCH)                       // refill the buffer just consumed
      ISSUE_CHUNK(buf ? tb1 : tb0, c + 2 * S);
    buf ^= 1;
  }
}

// ---- stats A: per-(level,block) online-softmax partials over logits (2 MB) ----
__global__ __launch_bounds__(256) void k_stats(const float* __restrict__ logits,
                                               float2* __restrict__ part, int N)
{
  const int lvl = blockIdx.y;
  const float* __restrict__ lg = logits + (size_t)lvl * N;
  float m = -INFINITY, s = 0.f;
  for (int i = blockIdx.x * 256 + threadIdx.x; i < N; i += NSB * 256) {
    float d  = lg[i];
    float Mn = fmaxf(m, d);
    s = s * __expf(m - Mn) + __expf(d - Mn);
    m = Mn;
  }
  const int lane = threadIdx.x & 63;
  const int wid  = threadIdx.x >> 6;
  #pragma unroll
  for (int o = 32; o; o >>= 1) {
    float mo = __shfl_xor(m, o), so = __shfl_xor(s, o);
    float Mn = fmaxf(m, mo);
    if (Mn > -INFINITY) { s = s * __expf(m - Mn) + so * __expf(mo - Mn); m = Mn; }
  }
  __shared__ float smM[4], smS[4];
  if (lane == 0) { smM[wid] = m; smS[wid] = s; }
  __syncthreads();
  if (threadIdx.x == 0) {
    float M = smM[0], Ss = smS[0];
    #pragma unroll
    for (int i = 1; i < 4; i++) {
      float Mn = fmaxf(M, smM[i]);
      if (Mn > -INFINITY) { Ss = Ss * __expf(M - Mn) + smS[i] * __expf(smM[i] - Mn); M = Mn; }
    }
    part[lvl * NSB + blockIdx.x] = make_float2(M, Ss);
  }
}

// ---- stats B: combine NSB partials per level -> (M, S) ----
__global__ __launch_bounds__(320) void k_reduce(const float2* __restrict__ part,
                                                float2* __restrict__ stats)
{
  const int lvl  = threadIdx.x >> 6;
  const int lane = threadIdx.x & 63;
  float m = -INFINITY, s = 0.f;
  if (lane < NSB) { float2 ps = part[lvl * NSB + lane]; m = ps.x; s = ps.y; }
  #pragma unroll
  for (int o = 32; o; o >>= 1) {
    float mo = __shfl_xor(m, o), so = __shfl_xor(s, o);
    float Mn = fmaxf(m, mo);
    if (Mn > -INFINITY) { s = s * __expf(m - Mn) + so * __expf(mo - Mn); m = Mn; }
  }
  if (lane == 0) stats[lvl] = make_float2(m, s);
}

// ---- pass 2: weights + fused output ----
__global__ __launch_bounds__(256) void k_pass2(Ptrs pt, const float* __restrict__ logits,
                                               const float2* __restrict__ stats,
                                               float* __restrict__ out, int N)
{
  const int lane = threadIdx.x & 63;
  const int wid  = threadIdx.x >> 6;
  float M[NLVL], Si[NLVL];
  #pragma unroll
  for (int l = 0; l < NLVL; l++) { float2 st = stats[l]; M[l] = st.x; Si[l] = 1.f / st.y; }

  const int gw = blockIdx.x * 4 + wid;
  const int nw = gridDim.x * 4;
  for (int n = gw; n < N; n += nw) {
    float wl[NLVL], t = 0.f;
    #pragma unroll
    for (int l = 0; l < NLVL; l++) {
      float e = __expf(logits[(size_t)l * N + n] - M[l]) * Si[l];
      wl[l] = e; t += e;
    }
    const float inv = 1.f / t;
    float4 acc = make_float4(0.f, 0.f, 0.f, 0.f);
    #pragma unroll
    for (int l = 0; l < NLVL; l++) {
      float4 pv = *reinterpret_cast<const float4*>(pt.p[l] + (size_t)n * DIM + lane * 4);
      float c = wl[l] * inv;
      acc.x += c * pv.x; acc.y += c * pv.y; acc.z += c * pv.z; acc.w += c * pv.w;
    }
    *reinterpret_cast<float4*>(out + (size_t)n * DIM + lane * 4) = acc;
  }
}

extern "C" void kernel_launch(void* const* d_in, const int* in_sizes, int n_in,
                              void* d_out, int out_size, void* d_ws, size_t ws_size,
                              hipStream_t stream)
{
  Ptrs pt;
  for (int l = 0; l < NLVL; l++) {
    pt.p[l] = (const float*)d_in[l];
    pt.W[l] = (const float*)d_in[5 + 2 * l];
    pt.b[l] = (const float*)d_in[6 + 2 * l];
  }
  const int N = in_sizes[0] / DIM;             // 100000

  char* ws = (char*)d_ws;
  size_t logits_bytes = ((size_t)NLVL * N * sizeof(float) + 255) & ~(size_t)255;
  float*  logits = (float*)ws;
  float2* part   = (float2*)(ws + logits_bytes);
  float2* stats  = part + NLVL * NSB;

  k_pass1 <<<NB1,             128, 0, stream>>>(pt, logits, N);
  k_stats <<<dim3(NSB, NLVL), 256, 0, stream>>>(logits, part, N);
  k_reduce<<<1,               320, 0, stream>>>(part, stats);
  k_pass2 <<<2048,            256, 0, stream>>>(pt, logits, stats, (float*)d_out, N);
}